// Round 6
// baseline (177.193 us; speedup 1.0000x reference)
//
#include <hip/hip_runtime.h>
#include <hip/hip_fp16.h>
#include <cstdint>

#define N_NODES 50000
#define N_EDGES 800000
#define N_FEAT 256
#define HIDDEN 128
#define N_CLASSES 40
#define NBUCKET 196         // dst >> 8
#define EPB 3125            // edges per partition block (256 * 3125 = 800000)
#define BCAP 8192           // bucket capacity in ebuf (max count ~4400)
#define ROWS_PAD 50048      // 782 * 64
#define G1_BLOCKS 782       // ROWS_PAD / 64
#define H2S 64              // h2 row stride (halves) = 128 B aligned rows
#define LROW 136            // agg1 LDS row stride in ushorts (272 B, 16B-aligned + bank skew)

typedef _Float16 half8 __attribute__((ext_vector_type(8)));
typedef __fp16 fp16x2 __attribute__((ext_vector_type(2)));
typedef __attribute__((ext_vector_type(4))) float f32x4;

__device__ inline ushort f2h(float f) {
    return __half_as_ushort(__float2half_rn(f));
}
__device__ inline __half2 u2h2(uint u) {
    union { uint u; __half2 h; } v; v.u = u; return v.h;
}
// replicate high half of u into both halves (weight rebuild after 1-word shfl)
__device__ inline uint wrep(uint u) {
    uint t = u >> 16;
    return (t << 16) | t;
}

// ---------------- 1) partition edges into fixed-capacity buckets + W1/W2 repack ----------------
// NO global per-node atomics (round-2 lesson: 800k random global atomicAdd = +26us).

__global__ __launch_bounds__(256) void partition_repack(
        const int* __restrict__ src, const int* __restrict__ dst,
        int* __restrict__ cursor, uint* __restrict__ ebuf,
        const float* __restrict__ W1, ushort* __restrict__ Bp1,
        const float* __restrict__ W2, ushort* __restrict__ Bp2) {
    __shared__ int h[NBUCKET];
    __shared__ int base[NBUCKET];
    __shared__ int cur[NBUCKET];
    int blk = blockIdx.x, t = threadIdx.x;
    int gid = blk * 256 + t;
    if (gid < 32768) {       // W1 repack into MFMA B-frag order (f16)
        int j = gid & 7, lane = (gid >> 3) & 63, kt = (gid >> 9) & 7, nt = gid >> 12;
        int k = kt * 32 + (lane >> 4) * 8 + j;
        int n = nt * 16 + (lane & 15);
        Bp1[gid] = f2h(W1[k * HIDDEN + n]);
    } else if (gid < 32768 + 6144) {   // W2 repack (3 nt * 4 kt * 64 * 8)
        int i2 = gid - 32768;
        int j = i2 & 7, lane = (i2 >> 3) & 63, kt = (i2 >> 9) & 3, nt = i2 >> 11;
        int k = kt * 32 + (lane >> 4) * 8 + j;
        int n = nt * 16 + (lane & 15);
        Bp2[i2] = (n < N_CLASSES) ? f2h(W2[k * N_CLASSES + n]) : (ushort)0;
    }
    if (t < NBUCKET) { h[t] = 0; cur[t] = 0; }
    __syncthreads();
    int eb = blk * EPB;
    for (int i = t; i < EPB; i += 256)
        atomicAdd(&h[dst[eb + i] >> 8], 1);
    __syncthreads();
    if (t < NBUCKET)
        base[t] = (h[t] > 0) ? atomicAdd(&cursor[t], h[t]) : 0;
    __syncthreads();
    for (int i = t; i < EPB; i += 256) {
        int d = dst[eb + i], sv = src[eb + i];
        int bk = d >> 8;
        int p = base[bk] + atomicAdd(&cur[bk], 1);
        ebuf[bk * BCAP + p] = ((uint)d << 16) | (uint)sv;
    }
}

// ---------------- 2) FUSED: bucket CSR build (blocks 0..195)  ||  GEMM1 (blocks 196..977) ----------

__global__ __launch_bounds__(256) void csr_gemm1(
        const uint* __restrict__ ebuf, const int* __restrict__ cursor,
        int* __restrict__ deg, float* __restrict__ dinv,
        int* __restrict__ rowptr, int* __restrict__ esrc,
        const float* __restrict__ x, const ushort* __restrict__ Bp,
        ushort* __restrict__ h1h) {
    if (blockIdx.x < NBUCKET) {
        // ----- per-bucket: degree + dinv + rowptr + CSR fill -----
        __shared__ int s[256];
        __shared__ int cnt[256];
        __shared__ int exc[256];
        __shared__ int cur[256];
        int b = blockIdx.x, t = threadIdx.x;
        s[t] = (t < NBUCKET) ? cursor[t] : 0;
        __syncthreads();
        for (int off = 1; off < 256; off <<= 1) {
            int t2 = 0;
            if (t >= off) t2 = s[t - off];
            __syncthreads();
            s[t] += t2;
            __syncthreads();
        }
        int beg = (b > 0) ? s[b - 1] : 0;      // CSR start of bucket b
        int ecnt = s[b] - beg;                 // edges in bucket b
        __syncthreads();
        cnt[t] = 0;
        cur[t] = 0;
        __syncthreads();
        const uint* eb = ebuf + (size_t)b * BCAP;
        for (int i = t; i < ecnt; i += 256)
            atomicAdd(&cnt[(eb[i] >> 16) & 255], 1);
        __syncthreads();
        int d = cnt[t];
        s[t] = d;
        __syncthreads();
        for (int off = 1; off < 256; off <<= 1) {
            int t2 = 0;
            if (t >= off) t2 = s[t - off];
            __syncthreads();
            s[t] += t2;
            __syncthreads();
        }
        exc[t] = s[t] - d;
        int node = b * 256 + t;
        if (node < N_NODES) {
            deg[node] = d;
            dinv[node] = rsqrtf((float)(d + 1));   // +1 self-loop
            rowptr[node] = beg + exc[t];
        }
        __syncthreads();
        for (int i = t; i < ecnt; i += 256) {
            uint u = eb[i];
            int dl = (int)(u >> 16) & 255;
            int pos = beg + exc[dl] + atomicAdd(&cur[dl], 1);
            esrc[pos] = (int)(u & 0xffffu);
        }
    } else {
        // ----- GEMM1: h1h[N,128] = f16(x[N,256]) @ W1  (MFMA f16, no LDS) -----
        int t = threadIdx.x;
        int lane = t & 63, w = t >> 6;
        int r = lane & 15, q = lane >> 4;
        int row0 = (blockIdx.x - NBUCKET) * 64;
        int arow = row0 + w * 16 + r;
        if (arow >= N_NODES) arow = N_NODES - 1;     // clamp: no fault, row discarded later
        const float* xrow = x + (size_t)arow * N_FEAT;
        f32x4 acc[8] = {};
        for (int kt = 0; kt < 8; ++kt) {
            float4 v0 = *(const float4*)(xrow + kt * 32 + q * 8);
            float4 v1 = *(const float4*)(xrow + kt * 32 + q * 8 + 4);
            union { fp16x2 p[4]; half8 a; } u;
            u.p[0] = __builtin_amdgcn_cvt_pkrtz(v0.x, v0.y);
            u.p[1] = __builtin_amdgcn_cvt_pkrtz(v0.z, v0.w);
            u.p[2] = __builtin_amdgcn_cvt_pkrtz(v1.x, v1.y);
            u.p[3] = __builtin_amdgcn_cvt_pkrtz(v1.z, v1.w);
#pragma unroll
            for (int nt = 0; nt < 8; ++nt) {
                half8 b = *(const half8*)(Bp + (((nt * 8 + kt) * 64) + lane) * 8);
                acc[nt] = __builtin_amdgcn_mfma_f32_16x16x32_f16(u.a, b, acc[nt], 0, 0, 0);
            }
        }
#pragma unroll
        for (int nt = 0; nt < 8; ++nt) {
            int col = nt * 16 + r;
#pragma unroll
            for (int reg = 0; reg < 4; ++reg) {
                int row = row0 + w * 16 + q * 4 + reg;
                if (row < N_NODES) h1h[(size_t)row * HIDDEN + col] = f2h(acc[nt][reg]);
            }
        }
    }
}

// ---------------- layer-1 aggregation: 16 nodes/block, quarter-wave per node ----------------
// 8 row-gathers in flight per burst; next-chunk (src,weight) prefetched under current FMAs.
// Overshoot edges (beyond a node's degree) carry weight 0 -> harmless, branch-free bursts.

__global__ __launch_bounds__(256) void agg1_w2(
        const int* __restrict__ rowptr, const int* __restrict__ deg,
        const int* __restrict__ esrc, const float* __restrict__ dinv,
        const ushort* __restrict__ h1h, const float* __restrict__ b1,
        const ushort* __restrict__ Bp2, ushort* __restrict__ h2h) {
    __shared__ ushort hag[16 * LROW];        // 16 rows x 272 B
    int t = threadIdx.x;
    int w = t >> 6, lane = t & 63;
    int q = lane >> 4, l15 = lane & 15;
    int n = w * 4 + q;                       // node slot 0..15
    int v = blockIdx.x * 16 + n;             // grid 3125 -> v < 50000 exactly
    int beg = rowptr[v], d = deg[v];
    float dv = dinv[v];
    __half2 z = __float2half2_rn(0.f);
    __half2 cA0 = z, cA1 = z, cA2 = z, cA3 = z;   // chain A (even edges)
    __half2 cB0 = z, cB1 = z, cB2 = z, cB3 = z;   // chain B (odd edges)
    {   // self-loop
        uint4 hv = *(const uint4*)(h1h + (size_t)v * HIDDEN + l15 * 8);
        __half2 gs = __float2half2_rn(dv * dv);
        cA0 = __hfma2(u2h2(hv.x), gs, cA0);
        cA1 = __hfma2(u2h2(hv.y), gs, cA1);
        cA2 = __hfma2(u2h2(hv.z), gs, cA2);
        cA3 = __hfma2(u2h2(hv.w), gs, cA3);
    }
    // wave-uniform chunk count = max degree over the wave's 4 nodes
    int dmx = max(d, __shfl_xor(d, 16, 64));
    dmx = max(dmx, __shfl_xor(dmx, 32, 64));
    int qb = lane & 48;                      // quarter base lane
    // chunk-0 pack: (f16 weight, src); invalid lanes -> w=0
    int ep = (l15 < d) ? esrc[beg + l15] : 0;
    float wp = (l15 < d) ? dinv[ep] * dv : 0.f;
    int up = (int)(((uint)f2h(wp) << 16) | (uint)ep);

#define BURST8(J)                                                              \
    {                                                                          \
        int u0 = __shfl(up, qb + (J) + 0, 64);                                 \
        int u1 = __shfl(up, qb + (J) + 1, 64);                                 \
        int u2 = __shfl(up, qb + (J) + 2, 64);                                 \
        int u3 = __shfl(up, qb + (J) + 3, 64);                                 \
        int u4 = __shfl(up, qb + (J) + 4, 64);                                 \
        int u5 = __shfl(up, qb + (J) + 5, 64);                                 \
        int u6 = __shfl(up, qb + (J) + 6, 64);                                 \
        int u7 = __shfl(up, qb + (J) + 7, 64);                                 \
        uint4 g0 = *(const uint4*)(h1h + (size_t)(u0 & 0xffff) * HIDDEN + l15 * 8); \
        uint4 g1 = *(const uint4*)(h1h + (size_t)(u1 & 0xffff) * HIDDEN + l15 * 8); \
        uint4 g2 = *(const uint4*)(h1h + (size_t)(u2 & 0xffff) * HIDDEN + l15 * 8); \
        uint4 g3 = *(const uint4*)(h1h + (size_t)(u3 & 0xffff) * HIDDEN + l15 * 8); \
        uint4 g4 = *(const uint4*)(h1h + (size_t)(u4 & 0xffff) * HIDDEN + l15 * 8); \
        uint4 g5 = *(const uint4*)(h1h + (size_t)(u5 & 0xffff) * HIDDEN + l15 * 8); \
        uint4 g6 = *(const uint4*)(h1h + (size_t)(u6 & 0xffff) * HIDDEN + l15 * 8); \
        uint4 g7 = *(const uint4*)(h1h + (size_t)(u7 & 0xffff) * HIDDEN + l15 * 8); \
        __half2 w0 = u2h2(wrep((uint)u0));                                     \
        __half2 w1 = u2h2(wrep((uint)u1));                                     \
        __half2 w2 = u2h2(wrep((uint)u2));                                     \
        __half2 w3 = u2h2(wrep((uint)u3));                                     \
        __half2 w4 = u2h2(wrep((uint)u4));                                     \
        __half2 w5 = u2h2(wrep((uint)u5));                                     \
        __half2 w6 = u2h2(wrep((uint)u6));                                     \
        __half2 w7 = u2h2(wrep((uint)u7));                                     \
        cA0 = __hfma2(u2h2(g0.x), w0, cA0);                                    \
        cA1 = __hfma2(u2h2(g0.y), w0, cA1);                                    \
        cA2 = __hfma2(u2h2(g0.z), w0, cA2);                                    \
        cA3 = __hfma2(u2h2(g0.w), w0, cA3);                                    \
        cB0 = __hfma2(u2h2(g1.x), w1, cB0);                                    \
        cB1 = __hfma2(u2h2(g1.y), w1, cB1);                                    \
        cB2 = __hfma2(u2h2(g1.z), w1, cB2);                                    \
        cB3 = __hfma2(u2h2(g1.w), w1, cB3);                                    \
        cA0 = __hfma2(u2h2(g2.x), w2, cA0);                                    \
        cA1 = __hfma2(u2h2(g2.y), w2, cA1);                                    \
        cA2 = __hfma2(u2h2(g2.z), w2, cA2);                                    \
        cA3 = __hfma2(u2h2(g2.w), w2, cA3);                                    \
        cB0 = __hfma2(u2h2(g3.x), w3, cB0);                                    \
        cB1 = __hfma2(u2h2(g3.y), w3, cB1);                                    \
        cB2 = __hfma2(u2h2(g3.z), w3, cB2);                                    \
        cB3 = __hfma2(u2h2(g3.w), w3, cB3);                                    \
        cA0 = __hfma2(u2h2(g4.x), w4, cA0);                                    \
        cA1 = __hfma2(u2h2(g4.y), w4, cA1);                                    \
        cA2 = __hfma2(u2h2(g4.z), w4, cA2);                                    \
        cA3 = __hfma2(u2h2(g4.w), w4, cA3);                                    \
        cB0 = __hfma2(u2h2(g5.x), w5, cB0);                                    \
        cB1 = __hfma2(u2h2(g5.y), w5, cB1);                                    \
        cB2 = __hfma2(u2h2(g5.z), w5, cB2);                                    \
        cB3 = __hfma2(u2h2(g5.w), w5, cB3);                                    \
        cA0 = __hfma2(u2h2(g6.x), w6, cA0);                                    \
        cA1 = __hfma2(u2h2(g6.y), w6, cA1);                                    \
        cA2 = __hfma2(u2h2(g6.z), w6, cA2);                                    \
        cA3 = __hfma2(u2h2(g6.w), w6, cA3);                                    \
        cB0 = __hfma2(u2h2(g7.x), w7, cB0);                                    \
        cB1 = __hfma2(u2h2(g7.y), w7, cB1);                                    \
        cB2 = __hfma2(u2h2(g7.z), w7, cB2);                                    \
        cB3 = __hfma2(u2h2(g7.w), w7, cB3);                                    \
    }

    for (int c = 0; c < dmx; c += 16) {
        // prefetch next chunk's (src, weight) under this chunk's gathers/FMAs
        int nidx = c + 16 + l15;
        int en = 0; float wn = 0.f;
        if ((c + 16 < dmx) && (nidx < d)) { en = esrc[beg + nidx]; wn = dinv[en] * dv; }
        int lim = dmx - c;
        BURST8(0)
        if (lim > 8) BURST8(8)
        up = (int)(((uint)f2h(wn) << 16) | (uint)en);
    }
#undef BURST8
    // combine chains in fp32, bias + relu (quarter owns full row: NO fold)
    float2 fA0 = __half22float2(cA0), fB0 = __half22float2(cB0);
    float2 fA1 = __half22float2(cA1), fB1 = __half22float2(cB1);
    float2 fA2 = __half22float2(cA2), fB2 = __half22float2(cB2);
    float2 fA3 = __half22float2(cA3), fB3 = __half22float2(cB3);
    float a0 = fA0.x + fB0.x, a1 = fA0.y + fB0.y;
    float a2 = fA1.x + fB1.x, a3 = fA1.y + fB1.y;
    float a4 = fA2.x + fB2.x, a5 = fA2.y + fB2.y;
    float a6 = fA3.x + fB3.x, a7 = fA3.y + fB3.y;
    float4 bb0 = ((const float4*)b1)[l15 * 2];
    float4 bb1 = ((const float4*)b1)[l15 * 2 + 1];
    a0 += bb0.x; a1 += bb0.y; a2 += bb0.z; a3 += bb0.w;
    a4 += bb1.x; a5 += bb1.y; a6 += bb1.z; a7 += bb1.w;
    a0 = a0 > 0.f ? a0 : 0.f;  a1 = a1 > 0.f ? a1 : 0.f;
    a2 = a2 > 0.f ? a2 : 0.f;  a3 = a3 > 0.f ? a3 : 0.f;
    a4 = a4 > 0.f ? a4 : 0.f;  a5 = a5 > 0.f ? a5 : 0.f;
    a6 = a6 > 0.f ? a6 : 0.f;  a7 = a7 > 0.f ? a7 : 0.f;
    uint4 ov;
    ov.x = ((uint)f2h(a1) << 16) | (uint)f2h(a0);
    ov.y = ((uint)f2h(a3) << 16) | (uint)f2h(a2);
    ov.z = ((uint)f2h(a5) << 16) | (uint)f2h(a4);
    ov.w = ((uint)f2h(a7) << 16) | (uint)f2h(a6);
    *(uint4*)(&hag[n * LROW + l15 * 8]) = ov;    // 16B aligned (LROW*2=272, l15*16)
    __syncthreads();
    // GEMM2: one 16x128 A-tile x Bp2 -> 16 nodes x 40 cols. Waves 0..2 each do one nt.
    if (w < 3) {
        int r = lane & 15;                   // output col within tile / A row
        f32x4 acc = {};
#pragma unroll
        for (int kt = 0; kt < 4; ++kt) {
            half8 a = *(const half8*)(&hag[r * LROW + kt * 32 + q * 8]);
            half8 b = *(const half8*)(Bp2 + (((w * 4 + kt) * 64) + lane) * 8);
            acc = __builtin_amdgcn_mfma_f32_16x16x32_f16(a, b, acc, 0, 0, 0);
        }
        int col = w * 16 + r;
        if (col < N_CLASSES) {
            int vb = blockIdx.x * 16 + q * 4;
#pragma unroll
            for (int reg = 0; reg < 4; ++reg)
                h2h[(size_t)(vb + reg) * H2S + col] = f2h(acc[reg]);
        }
    }
}

// ---------------- layer-2 aggregation + bias + log_softmax (2 nodes/wave, 16 loads in flight) ----

__global__ __launch_bounds__(256) void agg2_lsm(
        const int* __restrict__ rowptr, const int* __restrict__ deg,
        const int* __restrict__ esrc, const float* __restrict__ dinv,
        const ushort* __restrict__ h2h, const float* __restrict__ b2,
        float* __restrict__ out) {
    int t = threadIdx.x;
    int w = t >> 6, lane = t & 63;
    int half = lane >> 5, l = lane & 31;
    int v = blockIdx.x * 8 + w * 2 + half;   // grid 6250 -> v < 50000 always
    int beg = rowptr[v], d = deg[v];
    float dv = dinv[v];
    __half2 z = __float2half2_rn(0.f);
    __half2 cA = z, cB = z;
    {   // self-loop (l<20 meaningful; rest discarded)
        uint hv = *(const uint*)(h2h + (size_t)v * H2S + l * 2);
        cA = __hfma2(u2h2(hv), __float2half2_rn(dv * dv), cA);
    }
    int e_l = (l < d) ? esrc[beg + l] : 0;
    float wd = (l < d) ? dinv[e_l] * dv : 0.f;
    int up = (int)(((uint)f2h(wd) << 16) | (uint)e_l);
    int dm = min(d, 32);
    int base = half * 32;
    // branch-free 16-deep bursts; overshoot edges carry weight 0 -> harmless
    for (int i = 0; i < dm; i += 16) {
        int u0  = __shfl(up, base + i + 0, 64);
        int u1  = __shfl(up, base + i + 1, 64);
        int u2  = __shfl(up, base + i + 2, 64);
        int u3  = __shfl(up, base + i + 3, 64);
        int u4  = __shfl(up, base + i + 4, 64);
        int u5  = __shfl(up, base + i + 5, 64);
        int u6  = __shfl(up, base + i + 6, 64);
        int u7  = __shfl(up, base + i + 7, 64);
        int u8  = __shfl(up, base + i + 8, 64);
        int u9  = __shfl(up, base + i + 9, 64);
        int u10 = __shfl(up, base + i + 10, 64);
        int u11 = __shfl(up, base + i + 11, 64);
        int u12 = __shfl(up, base + i + 12, 64);
        int u13 = __shfl(up, base + i + 13, 64);
        int u14 = __shfl(up, base + i + 14, 64);
        int u15 = __shfl(up, base + i + 15, 64);
        uint h0  = *(const uint*)(h2h + (size_t)(u0  & 0xffff) * H2S + l * 2);
        uint h1  = *(const uint*)(h2h + (size_t)(u1  & 0xffff) * H2S + l * 2);
        uint h2  = *(const uint*)(h2h + (size_t)(u2  & 0xffff) * H2S + l * 2);
        uint h3  = *(const uint*)(h2h + (size_t)(u3  & 0xffff) * H2S + l * 2);
        uint h4  = *(const uint*)(h2h + (size_t)(u4  & 0xffff) * H2S + l * 2);
        uint h5  = *(const uint*)(h2h + (size_t)(u5  & 0xffff) * H2S + l * 2);
        uint h6  = *(const uint*)(h2h + (size_t)(u6  & 0xffff) * H2S + l * 2);
        uint h7  = *(const uint*)(h2h + (size_t)(u7  & 0xffff) * H2S + l * 2);
        uint h8  = *(const uint*)(h2h + (size_t)(u8  & 0xffff) * H2S + l * 2);
        uint h9  = *(const uint*)(h2h + (size_t)(u9  & 0xffff) * H2S + l * 2);
        uint h10 = *(const uint*)(h2h + (size_t)(u10 & 0xffff) * H2S + l * 2);
        uint h11 = *(const uint*)(h2h + (size_t)(u11 & 0xffff) * H2S + l * 2);
        uint h12 = *(const uint*)(h2h + (size_t)(u12 & 0xffff) * H2S + l * 2);
        uint h13 = *(const uint*)(h2h + (size_t)(u13 & 0xffff) * H2S + l * 2);
        uint h14 = *(const uint*)(h2h + (size_t)(u14 & 0xffff) * H2S + l * 2);
        uint h15 = *(const uint*)(h2h + (size_t)(u15 & 0xffff) * H2S + l * 2);
        cA = __hfma2(u2h2(h0),  u2h2(wrep((uint)u0)),  cA);
        cB = __hfma2(u2h2(h1),  u2h2(wrep((uint)u1)),  cB);
        cA = __hfma2(u2h2(h2),  u2h2(wrep((uint)u2)),  cA);
        cB = __hfma2(u2h2(h3),  u2h2(wrep((uint)u3)),  cB);
        cA = __hfma2(u2h2(h4),  u2h2(wrep((uint)u4)),  cA);
        cB = __hfma2(u2h2(h5),  u2h2(wrep((uint)u5)),  cB);
        cA = __hfma2(u2h2(h6),  u2h2(wrep((uint)u6)),  cA);
        cB = __hfma2(u2h2(h7),  u2h2(wrep((uint)u7)),  cB);
        cA = __hfma2(u2h2(h8),  u2h2(wrep((uint)u8)),  cA);
        cB = __hfma2(u2h2(h9),  u2h2(wrep((uint)u9)),  cB);
        cA = __hfma2(u2h2(h10), u2h2(wrep((uint)u10)), cA);
        cB = __hfma2(u2h2(h11), u2h2(wrep((uint)u11)), cB);
        cA = __hfma2(u2h2(h12), u2h2(wrep((uint)u12)), cA);
        cB = __hfma2(u2h2(h13), u2h2(wrep((uint)u13)), cB);
        cA = __hfma2(u2h2(h14), u2h2(wrep((uint)u14)), cA);
        cB = __hfma2(u2h2(h15), u2h2(wrep((uint)u15)), cB);
    }
    for (int i = 32; i < d; ++i) {           // rare deg>32 tail
        int s = esrc[beg + i];
        float g = dinv[s] * dv;
        uint hs = *(const uint*)(h2h + (size_t)s * H2S + l * 2);
        cA = __hfma2(u2h2(hs), __float2half2_rn(g), cA);
    }
    float2 fA = __half22float2(cA);
    float2 fB = __half22float2(cB);
    float ax = fA.x + fB.x, ay = fA.y + fB.y;
    if (l < 20) {
        float2 bb = ((const float2*)b2)[l];
        ax += bb.x; ay += bb.y;
    }
    float m = (l < 20) ? fmaxf(ax, ay) : -INFINITY;
#pragma unroll
    for (int off = 16; off; off >>= 1) m = fmaxf(m, __shfl_xor(m, off, 64));
    float e = (l < 20) ? (expf(ax - m) + expf(ay - m)) : 0.f;
#pragma unroll
    for (int off = 16; off; off >>= 1) e += __shfl_xor(e, off, 64);
    float ls = logf(e);
    if (l < 20) {
        float2 o;
        o.x = ax - m - ls;
        o.y = ay - m - ls;
        ((float2*)(out + (size_t)v * N_CLASSES))[l] = o;
    }
}

// ---------------- launch ----------------

extern "C" void kernel_launch(void* const* d_in, const int* in_sizes, int n_in,
                              void* d_out, int out_size, void* d_ws, size_t ws_size,
                              hipStream_t stream) {
    const float* x  = (const float*)d_in[0];
    const int*   ei = (const int*)d_in[1];
    const float* W1 = (const float*)d_in[2];
    const float* b1 = (const float*)d_in[3];
    const float* W2 = (const float*)d_in[4];
    const float* b2 = (const float*)d_in[5];
    const int* src = ei;
    const int* dst = ei + N_EDGES;
    float* out = (float*)d_out;

    char* ws = (char*)d_ws;
    size_t off = 0;
    auto alloc = [&](size_t bytes) {
        void* p = ws + off;
        off += (bytes + 255) & ~(size_t)255;
        return p;
    };
    int*    cursor = (int*)alloc((size_t)NBUCKET * 4);
    int*    deg    = (int*)alloc((size_t)N_NODES * 4);
    float*  dinv   = (float*)alloc((size_t)N_NODES * 4);
    int*    rowptr = (int*)alloc((size_t)N_NODES * 4);
    uint*   ebuf   = (uint*)alloc((size_t)NBUCKET * BCAP * 4);
    int*    esrc   = (int*)alloc((size_t)N_EDGES * 4);
    ushort* Bp1    = (ushort*)alloc((size_t)32768 * 2);
    ushort* Bp2    = (ushort*)alloc((size_t)6144 * 2);
    ushort* h1h    = (ushort*)alloc((size_t)ROWS_PAD * HIDDEN * 2);
    ushort* h2h    = (ushort*)alloc((size_t)ROWS_PAD * H2S * 2);

    // --- preprocessing: tiny memset + partition ---
    (void)hipMemsetAsync(cursor, 0, (size_t)NBUCKET * 4, stream);
    partition_repack<<<256, 256, 0, stream>>>(src, dst, cursor, ebuf, W1, Bp1, W2, Bp2);

    // --- fused CSR-build || GEMM1 (independent halves, co-scheduled) ---
    csr_gemm1<<<NBUCKET + G1_BLOCKS, 256, 0, stream>>>(
        ebuf, cursor, deg, dinv, rowptr, esrc, x, Bp1, h1h);

    // --- agg1 (16 nodes/block, 8-deep gather bursts, LDS-staged tile GEMM2) ---
    agg1_w2<<<N_NODES / 16, 256, 0, stream>>>(rowptr, deg, esrc, dinv, h1h, b1, Bp2, h2h);

    // --- agg2 + bias + log_softmax (16-deep bursts) ---
    agg2_lsm<<<N_NODES / 8, 256, 0, stream>>>(rowptr, deg, esrc, dinv, h2h, b2, out);
}

// Round 7
// 168.390 us; speedup vs baseline: 1.0523x; 1.0523x over previous
//
#include <hip/hip_runtime.h>
#include <hip/hip_fp16.h>
#include <cstdint>

#define N_NODES 50000
#define N_EDGES 800000
#define N_FEAT 256
#define HIDDEN 128
#define N_CLASSES 40
#define NBUCKET 196         // dst >> 8
#define EPB 3125            // edges per partition block (256 * 3125 = 800000)
#define BCAP 8192           // bucket capacity in ebuf (max count ~4400)
#define ROWS_PAD 50048      // 782 * 64
#define G1_BLOCKS 782       // ROWS_PAD / 64
#define H2S 64              // h2 row stride (halves) = 128 B aligned rows
#define LROW 136            // agg1 LDS row stride in ushorts (272 B, 16B-aligned + bank skew)

typedef _Float16 half8 __attribute__((ext_vector_type(8)));
typedef __fp16 fp16x2 __attribute__((ext_vector_type(2)));
typedef __attribute__((ext_vector_type(4))) float f32x4;
typedef __attribute__((ext_vector_type(2))) float f32x2;

__device__ inline ushort f2h(float f) {
    return __half_as_ushort(__float2half_rn(f));
}
__device__ inline float h2f_u(uint us) {
    union { ushort u; __half h; } v; v.u = (ushort)us; return __half2float(v.h);
}
__device__ inline __half2 u2h2(uint u) {
    union { uint u; __half2 h; } v; v.u = u; return v.h;
}
// replicate high half of u into both halves (weight rebuild after 1-word shfl)
__device__ inline uint wrep(uint u) {
    uint t = u >> 16;
    return (t << 16) | t;
}
// packed 2xf32 fma (compiler emits v_pk_fma_f32)
__device__ inline f32x2 pkfma(f32x2 a, f32x2 w, f32x2 c) {
    f32x2 r;
    r.x = __builtin_fmaf(a.x, w.x, c.x);
    r.y = __builtin_fmaf(a.y, w.y, c.y);
    return r;
}

// ---------------- 1) partition edges into fixed-capacity buckets + W1/W2 repack ----------------
// NO global per-node atomics (round-2 lesson: 800k random global atomicAdd = +26us).

__global__ __launch_bounds__(256) void partition_repack(
        const int* __restrict__ src, const int* __restrict__ dst,
        int* __restrict__ cursor, uint* __restrict__ ebuf,
        const float* __restrict__ W1, ushort* __restrict__ Bp1,
        const float* __restrict__ W2, ushort* __restrict__ Bp2) {
    __shared__ int h[NBUCKET];
    __shared__ int base[NBUCKET];
    __shared__ int cur[NBUCKET];
    int blk = blockIdx.x, t = threadIdx.x;
    int gid = blk * 256 + t;
    if (gid < 32768) {       // W1 repack into MFMA B-frag order (f16)
        int j = gid & 7, lane = (gid >> 3) & 63, kt = (gid >> 9) & 7, nt = gid >> 12;
        int k = kt * 32 + (lane >> 4) * 8 + j;
        int n = nt * 16 + (lane & 15);
        Bp1[gid] = f2h(W1[k * HIDDEN + n]);
    } else if (gid < 32768 + 6144) {   // W2 repack (3 nt * 4 kt * 64 * 8)
        int i2 = gid - 32768;
        int j = i2 & 7, lane = (i2 >> 3) & 63, kt = (i2 >> 9) & 3, nt = i2 >> 11;
        int k = kt * 32 + (lane >> 4) * 8 + j;
        int n = nt * 16 + (lane & 15);
        Bp2[i2] = (n < N_CLASSES) ? f2h(W2[k * N_CLASSES + n]) : (ushort)0;
    }
    if (t < NBUCKET) { h[t] = 0; cur[t] = 0; }
    __syncthreads();
    int eb = blk * EPB;
    for (int i = t; i < EPB; i += 256)
        atomicAdd(&h[dst[eb + i] >> 8], 1);
    __syncthreads();
    if (t < NBUCKET)
        base[t] = (h[t] > 0) ? atomicAdd(&cursor[t], h[t]) : 0;
    __syncthreads();
    for (int i = t; i < EPB; i += 256) {
        int d = dst[eb + i], sv = src[eb + i];
        int bk = d >> 8;
        int p = base[bk] + atomicAdd(&cur[bk], 1);
        ebuf[bk * BCAP + p] = ((uint)d << 16) | (uint)sv;
    }
}

// ---------------- 2) FUSED: bucket CSR build (blocks 0..195)  ||  GEMM1 (blocks 196..977) ----------
// GEMM1 stores h1 as fp8 e4m3 -> 6.4 MB table: ~halves agg1 L2-miss count and nearly
// fits a 4 MiB XCD L2 (round-4 counter evidence: FETCH 83 -> 34.5 MB).

__global__ __launch_bounds__(256) void csr_gemm1(
        const uint* __restrict__ ebuf, const int* __restrict__ cursor,
        int* __restrict__ deg, float* __restrict__ dinv,
        int* __restrict__ rowptr, int* __restrict__ esrc,
        const float* __restrict__ x, const ushort* __restrict__ Bp,
        unsigned char* __restrict__ h1q) {
    if (blockIdx.x < NBUCKET) {
        // ----- per-bucket: degree + dinv + rowptr + CSR fill -----
        __shared__ int s[256];
        __shared__ int cnt[256];
        __shared__ int exc[256];
        __shared__ int cur[256];
        int b = blockIdx.x, t = threadIdx.x;
        s[t] = (t < NBUCKET) ? cursor[t] : 0;
        __syncthreads();
        for (int off = 1; off < 256; off <<= 1) {
            int t2 = 0;
            if (t >= off) t2 = s[t - off];
            __syncthreads();
            s[t] += t2;
            __syncthreads();
        }
        int beg = (b > 0) ? s[b - 1] : 0;      // CSR start of bucket b
        int ecnt = s[b] - beg;                 // edges in bucket b
        __syncthreads();
        cnt[t] = 0;
        cur[t] = 0;
        __syncthreads();
        const uint* eb = ebuf + (size_t)b * BCAP;
        for (int i = t; i < ecnt; i += 256)
            atomicAdd(&cnt[(eb[i] >> 16) & 255], 1);
        __syncthreads();
        int d = cnt[t];
        s[t] = d;
        __syncthreads();
        for (int off = 1; off < 256; off <<= 1) {
            int t2 = 0;
            if (t >= off) t2 = s[t - off];
            __syncthreads();
            s[t] += t2;
            __syncthreads();
        }
        exc[t] = s[t] - d;
        int node = b * 256 + t;
        if (node < N_NODES) {
            deg[node] = d;
            dinv[node] = rsqrtf((float)(d + 1));   // +1 self-loop
            rowptr[node] = beg + exc[t];
        }
        __syncthreads();
        for (int i = t; i < ecnt; i += 256) {
            uint u = eb[i];
            int dl = (int)(u >> 16) & 255;
            int pos = beg + exc[dl] + atomicAdd(&cur[dl], 1);
            esrc[pos] = (int)(u & 0xffffu);
        }
    } else {
        // ----- GEMM1: h1q[N,128] = fp8(f16(x[N,256]) @ W1)  (MFMA f16, no LDS) -----
        int t = threadIdx.x;
        int lane = t & 63, w = t >> 6;
        int r = lane & 15, q = lane >> 4;
        int row0 = (blockIdx.x - NBUCKET) * 64;
        int arow = row0 + w * 16 + r;
        if (arow >= N_NODES) arow = N_NODES - 1;     // clamp: no fault, row discarded later
        const float* xrow = x + (size_t)arow * N_FEAT;
        f32x4 acc[8] = {};
        for (int kt = 0; kt < 8; ++kt) {
            float4 v0 = *(const float4*)(xrow + kt * 32 + q * 8);
            float4 v1 = *(const float4*)(xrow + kt * 32 + q * 8 + 4);
            union { fp16x2 p[4]; half8 a; } u;
            u.p[0] = __builtin_amdgcn_cvt_pkrtz(v0.x, v0.y);
            u.p[1] = __builtin_amdgcn_cvt_pkrtz(v0.z, v0.w);
            u.p[2] = __builtin_amdgcn_cvt_pkrtz(v1.x, v1.y);
            u.p[3] = __builtin_amdgcn_cvt_pkrtz(v1.z, v1.w);
#pragma unroll
            for (int nt = 0; nt < 8; ++nt) {
                half8 b = *(const half8*)(Bp + (((nt * 8 + kt) * 64) + lane) * 8);
                acc[nt] = __builtin_amdgcn_mfma_f32_16x16x32_f16(u.a, b, acc[nt], 0, 0, 0);
            }
        }
#pragma unroll
        for (int nt = 0; nt < 8; ++nt) {
            int col = nt * 16 + r;
#pragma unroll
            for (int reg = 0; reg < 4; ++reg) {
                int row = row0 + w * 16 + q * 4 + reg;
                if (row < N_NODES) {
                    int enc = __builtin_amdgcn_cvt_pk_fp8_f32(acc[nt][reg], acc[nt][reg], 0, false);
                    h1q[(size_t)row * 128 + col] = (unsigned char)(enc & 0xff);
                }
            }
        }
    }
}

// ---------------- layer-1 aggregation: 16 nodes/block, quarter-wave per node, fp8 gather ------
// Quarter (16 lanes x uint2) covers one full 128B fp8 row. fp32 packed accumulation.
// 8 row-gathers in flight per burst; next-chunk (src,weight) prefetched under current FMAs.

__global__ __launch_bounds__(256) void agg1_w2(
        const int* __restrict__ rowptr, const int* __restrict__ deg,
        const int* __restrict__ esrc, const float* __restrict__ dinv,
        const unsigned char* __restrict__ h1q, const float* __restrict__ b1,
        const ushort* __restrict__ Bp2, ushort* __restrict__ h2h) {
    __shared__ ushort hag[16 * LROW];        // 16 rows x 272 B (f16 agg rows for GEMM2)
    int t = threadIdx.x;
    int w = t >> 6, lane = t & 63;
    int q = lane >> 4, l15 = lane & 15;
    int n = w * 4 + q;                       // node slot 0..15
    int v = blockIdx.x * 16 + n;             // grid 3125 -> v < 50000 exactly
    int beg = rowptr[v], d = deg[v];
    float dv = dinv[v];
    f32x2 zz; zz.x = 0.f; zz.y = 0.f;
    f32x2 aA[4] = {zz, zz, zz, zz};          // chain A: col pairs
    f32x2 aB[4] = {zz, zz, zz, zz};          // chain B
    {   // self-loop
        uint2 g = *(const uint2*)(h1q + (size_t)v * 128 + l15 * 8);
        float ws = dv * dv;
        f32x2 wv; wv.x = ws; wv.y = ws;
        aA[0] = pkfma(__builtin_amdgcn_cvt_pk_f32_fp8((int)g.x, false), wv, aA[0]);
        aA[1] = pkfma(__builtin_amdgcn_cvt_pk_f32_fp8((int)g.x, true),  wv, aA[1]);
        aA[2] = pkfma(__builtin_amdgcn_cvt_pk_f32_fp8((int)g.y, false), wv, aA[2]);
        aA[3] = pkfma(__builtin_amdgcn_cvt_pk_f32_fp8((int)g.y, true),  wv, aA[3]);
    }
    // wave-uniform chunk count = max degree over the wave's 4 nodes
    int dmx = max(d, __shfl_xor(d, 16, 64));
    dmx = max(dmx, __shfl_xor(dmx, 32, 64));
    int qb = lane & 48;                      // quarter base lane
    // chunk-0 pack: (f16 weight, src); invalid lanes -> w=0
    int ep = (l15 < d) ? esrc[beg + l15] : 0;
    float wp = (l15 < d) ? dinv[ep] * dv : 0.f;
    int up = (int)(((uint)f2h(wp) << 16) | (uint)ep);

#define EDGE_A(U, WV)                                                          \
    {                                                                          \
        uint2 g = *(const uint2*)(h1q + (size_t)((U) & 0xffff) * 128 + l15 * 8); \
        aA[0] = pkfma(__builtin_amdgcn_cvt_pk_f32_fp8((int)g.x, false), WV, aA[0]); \
        aA[1] = pkfma(__builtin_amdgcn_cvt_pk_f32_fp8((int)g.x, true),  WV, aA[1]); \
        aA[2] = pkfma(__builtin_amdgcn_cvt_pk_f32_fp8((int)g.y, false), WV, aA[2]); \
        aA[3] = pkfma(__builtin_amdgcn_cvt_pk_f32_fp8((int)g.y, true),  WV, aA[3]); \
    }
#define EDGE_B(U, WV)                                                          \
    {                                                                          \
        uint2 g = *(const uint2*)(h1q + (size_t)((U) & 0xffff) * 128 + l15 * 8); \
        aB[0] = pkfma(__builtin_amdgcn_cvt_pk_f32_fp8((int)g.x, false), WV, aB[0]); \
        aB[1] = pkfma(__builtin_amdgcn_cvt_pk_f32_fp8((int)g.x, true),  WV, aB[1]); \
        aB[2] = pkfma(__builtin_amdgcn_cvt_pk_f32_fp8((int)g.y, false), WV, aB[2]); \
        aB[3] = pkfma(__builtin_amdgcn_cvt_pk_f32_fp8((int)g.y, true),  WV, aB[3]); \
    }
#define BURST8(J)                                                              \
    {                                                                          \
        int u0 = __shfl(up, qb + (J) + 0, 64);                                 \
        int u1 = __shfl(up, qb + (J) + 1, 64);                                 \
        int u2 = __shfl(up, qb + (J) + 2, 64);                                 \
        int u3 = __shfl(up, qb + (J) + 3, 64);                                 \
        int u4 = __shfl(up, qb + (J) + 4, 64);                                 \
        int u5 = __shfl(up, qb + (J) + 5, 64);                                 \
        int u6 = __shfl(up, qb + (J) + 6, 64);                                 \
        int u7 = __shfl(up, qb + (J) + 7, 64);                                 \
        float w0 = h2f_u((uint)u0 >> 16), w1 = h2f_u((uint)u1 >> 16);          \
        float w2 = h2f_u((uint)u2 >> 16), w3 = h2f_u((uint)u3 >> 16);          \
        float w4 = h2f_u((uint)u4 >> 16), w5 = h2f_u((uint)u5 >> 16);          \
        float w6 = h2f_u((uint)u6 >> 16), w7 = h2f_u((uint)u7 >> 16);          \
        f32x2 wv0; wv0.x = w0; wv0.y = w0;                                     \
        f32x2 wv1; wv1.x = w1; wv1.y = w1;                                     \
        f32x2 wv2; wv2.x = w2; wv2.y = w2;                                     \
        f32x2 wv3; wv3.x = w3; wv3.y = w3;                                     \
        f32x2 wv4; wv4.x = w4; wv4.y = w4;                                     \
        f32x2 wv5; wv5.x = w5; wv5.y = w5;                                     \
        f32x2 wv6; wv6.x = w6; wv6.y = w6;                                     \
        f32x2 wv7; wv7.x = w7; wv7.y = w7;                                     \
        EDGE_A(u0, wv0) EDGE_B(u1, wv1) EDGE_A(u2, wv2) EDGE_B(u3, wv3)        \
        EDGE_A(u4, wv4) EDGE_B(u5, wv5) EDGE_A(u6, wv6) EDGE_B(u7, wv7)        \
    }

    for (int c = 0; c < dmx; c += 16) {
        // prefetch next chunk's (src, weight) under this chunk's gathers/FMAs
        int nidx = c + 16 + l15;
        int en = 0; float wn = 0.f;
        if ((c + 16 < dmx) && (nidx < d)) { en = esrc[beg + nidx]; wn = dinv[en] * dv; }
        int lim = dmx - c;
        BURST8(0)
        if (lim > 8) BURST8(8)
        up = (int)(((uint)f2h(wn) << 16) | (uint)en);
    }
#undef BURST8
#undef EDGE_A
#undef EDGE_B
    // combine chains (fp32 throughout), bias + relu (quarter owns full row: NO fold)
    float a0 = aA[0].x + aB[0].x, a1 = aA[0].y + aB[0].y;
    float a2 = aA[1].x + aB[1].x, a3 = aA[1].y + aB[1].y;
    float a4 = aA[2].x + aB[2].x, a5 = aA[2].y + aB[2].y;
    float a6 = aA[3].x + aB[3].x, a7 = aA[3].y + aB[3].y;
    float4 bb0 = ((const float4*)b1)[l15 * 2];
    float4 bb1 = ((const float4*)b1)[l15 * 2 + 1];
    a0 += bb0.x; a1 += bb0.y; a2 += bb0.z; a3 += bb0.w;
    a4 += bb1.x; a5 += bb1.y; a6 += bb1.z; a7 += bb1.w;
    a0 = a0 > 0.f ? a0 : 0.f;  a1 = a1 > 0.f ? a1 : 0.f;
    a2 = a2 > 0.f ? a2 : 0.f;  a3 = a3 > 0.f ? a3 : 0.f;
    a4 = a4 > 0.f ? a4 : 0.f;  a5 = a5 > 0.f ? a5 : 0.f;
    a6 = a6 > 0.f ? a6 : 0.f;  a7 = a7 > 0.f ? a7 : 0.f;
    uint4 ov;
    ov.x = ((uint)f2h(a1) << 16) | (uint)f2h(a0);
    ov.y = ((uint)f2h(a3) << 16) | (uint)f2h(a2);
    ov.z = ((uint)f2h(a5) << 16) | (uint)f2h(a4);
    ov.w = ((uint)f2h(a7) << 16) | (uint)f2h(a6);
    *(uint4*)(&hag[n * LROW + l15 * 8]) = ov;    // 16B aligned (LROW*2=272, l15*16)
    __syncthreads();
    // GEMM2: one 16x128 A-tile x Bp2 -> 16 nodes x 40 cols. Waves 0..2 each do one nt.
    if (w < 3) {
        int r = lane & 15;                   // output col within tile / A row
        f32x4 acc = {};
#pragma unroll
        for (int kt = 0; kt < 4; ++kt) {
            half8 a = *(const half8*)(&hag[r * LROW + kt * 32 + q * 8]);
            half8 b = *(const half8*)(Bp2 + (((w * 4 + kt) * 64) + lane) * 8);
            acc = __builtin_amdgcn_mfma_f32_16x16x32_f16(a, b, acc, 0, 0, 0);
        }
        int col = w * 16 + r;
        if (col < N_CLASSES) {
            int vb = blockIdx.x * 16 + q * 4;
#pragma unroll
            for (int reg = 0; reg < 4; ++reg)
                h2h[(size_t)(vb + reg) * H2S + col] = f2h(acc[reg]);
        }
    }
}

// ---------------- layer-2 aggregation + bias + log_softmax (2 nodes/wave, 16 loads in flight) ----

__global__ __launch_bounds__(256) void agg2_lsm(
        const int* __restrict__ rowptr, const int* __restrict__ deg,
        const int* __restrict__ esrc, const float* __restrict__ dinv,
        const ushort* __restrict__ h2h, const float* __restrict__ b2,
        float* __restrict__ out) {
    int t = threadIdx.x;
    int w = t >> 6, lane = t & 63;
    int half = lane >> 5, l = lane & 31;
    int v = blockIdx.x * 8 + w * 2 + half;   // grid 6250 -> v < 50000 always
    int beg = rowptr[v], d = deg[v];
    float dv = dinv[v];
    __half2 z = __float2half2_rn(0.f);
    __half2 cA = z, cB = z;
    {   // self-loop (l<20 meaningful; rest discarded)
        uint hv = *(const uint*)(h2h + (size_t)v * H2S + l * 2);
        cA = __hfma2(u2h2(hv), __float2half2_rn(dv * dv), cA);
    }
    int e_l = (l < d) ? esrc[beg + l] : 0;
    float wd = (l < d) ? dinv[e_l] * dv : 0.f;
    int up = (int)(((uint)f2h(wd) << 16) | (uint)e_l);
    int dm = min(d, 32);
    int base = half * 32;
    // branch-free 16-deep bursts; overshoot edges carry weight 0 -> harmless
    for (int i = 0; i < dm; i += 16) {
        int u0  = __shfl(up, base + i + 0, 64);
        int u1  = __shfl(up, base + i + 1, 64);
        int u2  = __shfl(up, base + i + 2, 64);
        int u3  = __shfl(up, base + i + 3, 64);
        int u4  = __shfl(up, base + i + 4, 64);
        int u5  = __shfl(up, base + i + 5, 64);
        int u6  = __shfl(up, base + i + 6, 64);
        int u7  = __shfl(up, base + i + 7, 64);
        int u8  = __shfl(up, base + i + 8, 64);
        int u9  = __shfl(up, base + i + 9, 64);
        int u10 = __shfl(up, base + i + 10, 64);
        int u11 = __shfl(up, base + i + 11, 64);
        int u12 = __shfl(up, base + i + 12, 64);
        int u13 = __shfl(up, base + i + 13, 64);
        int u14 = __shfl(up, base + i + 14, 64);
        int u15 = __shfl(up, base + i + 15, 64);
        uint h0  = *(const uint*)(h2h + (size_t)(u0  & 0xffff) * H2S + l * 2);
        uint h1  = *(const uint*)(h2h + (size_t)(u1  & 0xffff) * H2S + l * 2);
        uint h2  = *(const uint*)(h2h + (size_t)(u2  & 0xffff) * H2S + l * 2);
        uint h3  = *(const uint*)(h2h + (size_t)(u3  & 0xffff) * H2S + l * 2);
        uint h4  = *(const uint*)(h2h + (size_t)(u4  & 0xffff) * H2S + l * 2);
        uint h5  = *(const uint*)(h2h + (size_t)(u5  & 0xffff) * H2S + l * 2);
        uint h6  = *(const uint*)(h2h + (size_t)(u6  & 0xffff) * H2S + l * 2);
        uint h7  = *(const uint*)(h2h + (size_t)(u7  & 0xffff) * H2S + l * 2);
        uint h8  = *(const uint*)(h2h + (size_t)(u8  & 0xffff) * H2S + l * 2);
        uint h9  = *(const uint*)(h2h + (size_t)(u9  & 0xffff) * H2S + l * 2);
        uint h10 = *(const uint*)(h2h + (size_t)(u10 & 0xffff) * H2S + l * 2);
        uint h11 = *(const uint*)(h2h + (size_t)(u11 & 0xffff) * H2S + l * 2);
        uint h12 = *(const uint*)(h2h + (size_t)(u12 & 0xffff) * H2S + l * 2);
        uint h13 = *(const uint*)(h2h + (size_t)(u13 & 0xffff) * H2S + l * 2);
        uint h14 = *(const uint*)(h2h + (size_t)(u14 & 0xffff) * H2S + l * 2);
        uint h15 = *(const uint*)(h2h + (size_t)(u15 & 0xffff) * H2S + l * 2);
        cA = __hfma2(u2h2(h0),  u2h2(wrep((uint)u0)),  cA);
        cB = __hfma2(u2h2(h1),  u2h2(wrep((uint)u1)),  cB);
        cA = __hfma2(u2h2(h2),  u2h2(wrep((uint)u2)),  cA);
        cB = __hfma2(u2h2(h3),  u2h2(wrep((uint)u3)),  cB);
        cA = __hfma2(u2h2(h4),  u2h2(wrep((uint)u4)),  cA);
        cB = __hfma2(u2h2(h5),  u2h2(wrep((uint)u5)),  cB);
        cA = __hfma2(u2h2(h6),  u2h2(wrep((uint)u6)),  cA);
        cB = __hfma2(u2h2(h7),  u2h2(wrep((uint)u7)),  cB);
        cA = __hfma2(u2h2(h8),  u2h2(wrep((uint)u8)),  cA);
        cB = __hfma2(u2h2(h9),  u2h2(wrep((uint)u9)),  cB);
        cA = __hfma2(u2h2(h10), u2h2(wrep((uint)u10)), cA);
        cB = __hfma2(u2h2(h11), u2h2(wrep((uint)u11)), cB);
        cA = __hfma2(u2h2(h12), u2h2(wrep((uint)u12)), cA);
        cB = __hfma2(u2h2(h13), u2h2(wrep((uint)u13)), cB);
        cA = __hfma2(u2h2(h14), u2h2(wrep((uint)u14)), cA);
        cB = __hfma2(u2h2(h15), u2h2(wrep((uint)u15)), cB);
    }
    for (int i = 32; i < d; ++i) {           // rare deg>32 tail
        int s = esrc[beg + i];
        float g = dinv[s] * dv;
        uint hs = *(const uint*)(h2h + (size_t)s * H2S + l * 2);
        cA = __hfma2(u2h2(hs), __float2half2_rn(g), cA);
    }
    float2 fA = __half22float2(cA);
    float2 fB = __half22float2(cB);
    float ax = fA.x + fB.x, ay = fA.y + fB.y;
    if (l < 20) {
        float2 bb = ((const float2*)b2)[l];
        ax += bb.x; ay += bb.y;
    }
    float m = (l < 20) ? fmaxf(ax, ay) : -INFINITY;
#pragma unroll
    for (int off = 16; off; off >>= 1) m = fmaxf(m, __shfl_xor(m, off, 64));
    float e = (l < 20) ? (expf(ax - m) + expf(ay - m)) : 0.f;
#pragma unroll
    for (int off = 16; off; off >>= 1) e += __shfl_xor(e, off, 64);
    float ls = logf(e);
    if (l < 20) {
        float2 o;
        o.x = ax - m - ls;
        o.y = ay - m - ls;
        ((float2*)(out + (size_t)v * N_CLASSES))[l] = o;
    }
}

// ---------------- launch ----------------

extern "C" void kernel_launch(void* const* d_in, const int* in_sizes, int n_in,
                              void* d_out, int out_size, void* d_ws, size_t ws_size,
                              hipStream_t stream) {
    const float* x  = (const float*)d_in[0];
    const int*   ei = (const int*)d_in[1];
    const float* W1 = (const float*)d_in[2];
    const float* b1 = (const float*)d_in[3];
    const float* W2 = (const float*)d_in[4];
    const float* b2 = (const float*)d_in[5];
    const int* src = ei;
    const int* dst = ei + N_EDGES;
    float* out = (float*)d_out;

    char* ws = (char*)d_ws;
    size_t off = 0;
    auto alloc = [&](size_t bytes) {
        void* p = ws + off;
        off += (bytes + 255) & ~(size_t)255;
        return p;
    };
    int*    cursor = (int*)alloc((size_t)NBUCKET * 4);
    int*    deg    = (int*)alloc((size_t)N_NODES * 4);
    float*  dinv   = (float*)alloc((size_t)N_NODES * 4);
    int*    rowptr = (int*)alloc((size_t)N_NODES * 4);
    uint*   ebuf   = (uint*)alloc((size_t)NBUCKET * BCAP * 4);
    int*    esrc   = (int*)alloc((size_t)N_EDGES * 4);
    ushort* Bp1    = (ushort*)alloc((size_t)32768 * 2);
    ushort* Bp2    = (ushort*)alloc((size_t)6144 * 2);
    unsigned char* h1q = (unsigned char*)alloc((size_t)ROWS_PAD * 128);
    ushort* h2h    = (ushort*)alloc((size_t)ROWS_PAD * H2S * 2);

    // --- preprocessing: tiny memset + partition ---
    (void)hipMemsetAsync(cursor, 0, (size_t)NBUCKET * 4, stream);
    partition_repack<<<256, 256, 0, stream>>>(src, dst, cursor, ebuf, W1, Bp1, W2, Bp2);

    // --- fused CSR-build || GEMM1 (independent halves, co-scheduled) ---
    csr_gemm1<<<NBUCKET + G1_BLOCKS, 256, 0, stream>>>(
        ebuf, cursor, deg, dinv, rowptr, esrc, x, Bp1, h1q);

    // --- agg1 (16 nodes/block, fp8 gather table, LDS-staged tile GEMM2) ---
    agg1_w2<<<N_NODES / 16, 256, 0, stream>>>(rowptr, deg, esrc, dinv, h1q, b1, Bp2, h2h);

    // --- agg2 + bias + log_softmax (16-deep bursts) ---
    agg2_lsm<<<N_NODES / 8, 256, 0, stream>>>(rowptr, deg, esrc, dinv, h2h, b2, out);
}